// Round 17
// baseline (55.255 us; speedup 1.0000x reference)
//
#include <hip/hip_runtime.h>
#include <math.h>

#define NB   8
#define SEQ  2048
#define EMB  8
#define NH   4
#define NFF  2048
#define NTOK (NB*SEQ)          // 16384
#define LNEPS 1e-5f

typedef float v2f __attribute__((ext_vector_type(2)));

__device__ __forceinline__ float fexp2(float x) {
#if __has_builtin(__builtin_amdgcn_exp2f)
    return __builtin_amdgcn_exp2f(x);       // raw v_exp_f32 (~1 ulp)
#else
    return exp2f(x);
#endif
}

__device__ __forceinline__ float dot8(const float4& a, const float4& b,
                                      const float4& c, const float4& d) {
    return a.x*b.x + a.y*b.y + a.z*b.z + a.w*b.w
         + c.x*d.x + c.y*d.y + c.z*d.z + c.w*d.w;
}

// ---------------------------------------------------------------------------
// projH[(b*4+h)][s][2] = (x @ Wp^T) head-major, and W2T[f][e] = W2[e][f]
// ---------------------------------------------------------------------------
__global__ __launch_bounds__(128) void k_prep(const float* __restrict__ x,
                                              const float* __restrict__ Wp,
                                              const float* __restrict__ W2,
                                              float* __restrict__ projH,
                                              float* __restrict__ w2t) {
    int t = blockIdx.x * 128 + threadIdx.x;
    if (t < NTOK) {
        int b = t >> 11, s = t & (SEQ - 1);
        const float4* xr = (const float4*)(x + (size_t)t * EMB);
        float4 xa = xr[0], xb = xr[1];
        float o[8];
#pragma unroll
        for (int e = 0; e < 8; ++e) {
            const float4* wr = (const float4*)(Wp + e * EMB);
            o[e] = dot8(xa, wr[0], xb, wr[1]);
        }
#pragma unroll
        for (int h = 0; h < 4; ++h) {
            *(float2*)(projH + ((size_t)(b * 4 + h) * SEQ + s) * 2) =
                make_float2(o[2 * h], o[2 * h + 1]);
        }
    }
    if (t < NFF) {
        float o[8];
#pragma unroll
        for (int e = 0; e < 8; ++e) o[e] = W2[e * NFF + t];
        float4* wr = (float4*)(w2t + (size_t)t * EMB);
        wr[0] = make_float4(o[0], o[1], o[2], o[3]);
        wr[1] = make_float4(o[4], o[5], o[6], o[7]);
    }
}

// ---------------------------------------------------------------------------
// attention v5 (R16, unchanged): 4 queries/thread — halves LDS b128 reads
// per (q,k) pair vs v4.  16 key-subranges x 128 keys, QCA=64, grid 1024.
// Log2-domain staging (R14-proven): k' = k*C, one v_exp_f32 per pair.
// ---------------------------------------------------------------------------
#define QCA 64
__global__ __launch_bounds__(256) void k_attn(const float* __restrict__ projH,
                                              float* __restrict__ ctx) {
    __shared__ float Kx[SEQ];               // 8 KB  (pre-scaled by C)
    __shared__ float Ky[SEQ];               // 8 KB
    __shared__ float red[3][16][QCA];       // 12 KB

    int bid = blockIdx.x;
    int qc  = bid & 31;                     // 32 query chunks of 64
    int bh  = bid >> 5;                     // (b*4+h)

    const float C   = 1.01001959058f;       // sqrt(log2(e)/sqrt(2))
    const float RC  = 0.99008003302f;       // 1/C
    const float4* gsr = (const float4*)(projH + (size_t)bh * SEQ * 2);
#pragma unroll
    for (int ii = 0; ii < 4; ++ii) {
        int i = threadIdx.x + 256 * ii;
        float4 v = gsr[i];                  // keys 2i,2i+1: (x0,y0,x1,y1)
        *(float2*)&Kx[2 * i] = make_float2(v.x * C, v.z * C);
        *(float2*)&Ky[2 * i] = make_float2(v.y * C, v.w * C);
    }
    __syncthreads();

    int qg  = threadIdx.x & 15;             // 16 query groups of 4
    int sub = threadIdx.x >> 4;             // 16 key subranges of 128

    int q0 = qc * QCA + qg * 4;
    v2f qx2[4], qy2[4], l[4], ax[4], ay[4];
#pragma unroll
    for (int u = 0; u < 4; ++u) {
        float qx = Kx[q0 + u], qy = Ky[q0 + u];   // already x C
        qx2[u] = (v2f){qx, qx};
        qy2[u] = (v2f){qy, qy};
        l[u]  = (v2f){0.f, 0.f};
        ax[u] = (v2f){0.f, 0.f};
        ay[u] = (v2f){0.f, 0.f};
    }

    const float4* Kx4 = (const float4*)Kx;
    const float4* Ky4 = (const float4*)Ky;
    int j04 = sub * 32;                     // 128 keys = 32 float4
#pragma unroll 2
    for (int jj = 0; jj < 32; ++jj) {
        float4 kx = Kx4[j04 + jj];          // 4 distinct addrs/wave: broadcast
        float4 ky = Ky4[j04 + jj];
        v2f k0 = {kx.x, kx.y}, k1 = {kx.z, kx.w};
        v2f m0 = {ky.x, ky.y}, m1 = {ky.z, ky.w};
#pragma unroll
        for (int u = 0; u < 4; ++u) {
            v2f s0 = qx2[u] * k0 + qy2[u] * m0;   // pk mul/fma, log2-domain
            v2f s1 = qx2[u] * k1 + qy2[u] * m1;
            v2f p0, p1;
            p0.x = fexp2(s0.x); p0.y = fexp2(s0.y);
            p1.x = fexp2(s1.x); p1.y = fexp2(s1.y);
            l[u]  += p0;        l[u]  += p1;
            ax[u] += p0 * k0;   ax[u] += p1 * k1;
            ay[u] += p0 * m0;   ay[u] += p1 * m1;
        }
    }
#pragma unroll
    for (int u = 0; u < 4; ++u) {
        red[0][sub][qg * 4 + u] = l[u].x + l[u].y;
        red[1][sub][qg * 4 + u] = ax[u].x + ax[u].y;
        red[2][sub][qg * 4 + u] = ay[u].x + ay[u].y;
    }
    __syncthreads();

    if (threadIdx.x < QCA) {
        float L = 0.f, A0 = 0.f, A1 = 0.f;
#pragma unroll
        for (int s = 0; s < 16; ++s) {
            L  += red[0][s][threadIdx.x];
            A0 += red[1][s][threadIdx.x];
            A1 += red[2][s][threadIdx.x];
        }
        float inv = RC / L;                 // undo the C on staged k
        int b = bh >> 2, h = bh & 3;
        int qglob = qc * QCA + threadIdx.x;
        *(float2*)(ctx + ((size_t)b * SEQ + qglob) * EMB + 2 * h) =
            make_float2(A0 * inv, A1 * inv);
    }
}

// ---------------------------------------------------------------------------
// FUSED post+FFN v5 (R14, unchanged — best-measured ffn combo: strided-f,
// unroll 4, VGPR ~56, 4 waves/SIMD).  512 threads, TB=32, grid=512.
// sub = tid>>3, f = sub*32 + i (thread walks consecutive 32B rows: L1 line
// reuse).  tg=tid&7: 4 tokens/thread, 8-lane broadcast per row.  In-wave
// shfl reduce over lane bits 3-5, cross-wave LDS reduce, LN2 via 8-lane
// shuffles.
// ---------------------------------------------------------------------------
#define TB3  32                 // tokens per block
#define FCH3 32                 // f rows per thread
__global__ __launch_bounds__(512) void k_ffn3(const float* __restrict__ ctx,
                                              const float* __restrict__ x,
                                              const float* __restrict__ Wo,
                                              const float* __restrict__ g1,
                                              const float* __restrict__ b1,
                                              const float* __restrict__ W1,
                                              const float* __restrict__ bb1,
                                              const float* __restrict__ w2t,
                                              const float* __restrict__ bb2,
                                              const float* __restrict__ g2,
                                              const float* __restrict__ b2,
                                              float* __restrict__ out) {
    __shared__ float q_lds[TB3][8];         // 1 KB
    __shared__ float x1_lds[TB3][8];        // 1 KB
    __shared__ float red[8][TB3][8];        // 8 KB: per-wave partials

    int tid = threadIdx.x;

    // ---- prologue: post-attention for this block's 32 tokens (256 lanes) ----
    if (tid < TB3 * 8) {
        int tl = tid >> 3, e = tid & 7;
        int tok = blockIdx.x * TB3 + tl;
        const float4* cr = (const float4*)(ctx + (size_t)tok * EMB);
        float4 ca = cr[0], cb = cr[1];      // broadcast across the 8 lanes
        const float4* wr = (const float4*)(Wo + e * EMB);
        float ao = dot8(ca, wr[0], cb, wr[1]);
        float y = x[(size_t)tok * EMB + e] + ao;

        float s8 = y;
        s8 += __shfl_xor(s8, 1);
        s8 += __shfl_xor(s8, 2);
        s8 += __shfl_xor(s8, 4);
        float mu = s8 * 0.125f;
        float d  = y - mu;
        float vs = d * d;
        vs += __shfl_xor(vs, 1);
        vs += __shfl_xor(vs, 2);
        vs += __shfl_xor(vs, 4);
        float r = rsqrtf(vs * 0.125f + LNEPS);
        float v = d * r * g1[e] + b1[e];
        x1_lds[tl][e] = v;

        float p = __cosf(v);
        float t1 = __shfl_up(p, 1, 8); p = (e >= 1) ? p * t1 : p;
        float t2 = __shfl_up(p, 2, 8); p = (e >= 2) ? p * t2 : p;
        float t4 = __shfl_up(p, 4, 8); p = (e >= 4) ? p * t4 : p;
        q_lds[tl][e] = p;
    }
    __syncthreads();

    // ---- main FFN loop: 4 tokens x 32 sequential f rows per thread ----
    int tg  = tid & 7;                      // 8 token groups x 4 tokens
    int sub = tid >> 3;                     // 64 f-subranges
    int tl0 = tg * 4;

    float4 qa[4], qb[4];
#pragma unroll
    for (int k = 0; k < 4; ++k) {
        qa[k] = *(const float4*)&q_lds[tl0 + k][0];   // 8-lane broadcast
        qb[k] = *(const float4*)&q_lds[tl0 + k][4];
    }

    float acc[4][8];
#pragma unroll
    for (int k = 0; k < 4; ++k)
#pragma unroll
        for (int e = 0; e < 8; ++e) acc[k][e] = 0.f;

    int f0 = sub * FCH3;
#pragma unroll 4
    for (int i = 0; i < FCH3; ++i) {
        int f = f0 + i;                     // walks consecutive rows: L1 reuse
        const float4* w1r = (const float4*)(W1 + (size_t)f * EMB);
        float4 wa = w1r[0], wb = w1r[1];
        float bias = bb1[f];
        const float4* w2r = (const float4*)(w2t + (size_t)f * EMB);
        float4 va = w2r[0], vb = w2r[1];
#pragma unroll
        for (int k = 0; k < 4; ++k) {
            float hv = fmaxf(dot8(qa[k], wa, qb[k], wb) + bias, 0.f);
            acc[k][0] = fmaf(hv, va.x, acc[k][0]);
            acc[k][1] = fmaf(hv, va.y, acc[k][1]);
            acc[k][2] = fmaf(hv, va.z, acc[k][2]);
            acc[k][3] = fmaf(hv, va.w, acc[k][3]);
            acc[k][4] = fmaf(hv, vb.x, acc[k][4]);
            acc[k][5] = fmaf(hv, vb.y, acc[k][5]);
            acc[k][6] = fmaf(hv, vb.z, acc[k][6]);
            acc[k][7] = fmaf(hv, vb.w, acc[k][7]);
        }
    }

    // in-wave reduce across the 8 sub groups (lane bits 3..5)
#pragma unroll
    for (int k = 0; k < 4; ++k)
#pragma unroll
        for (int e = 0; e < 8; ++e) {
            float v = acc[k][e];
            v += __shfl_xor(v, 8);
            v += __shfl_xor(v, 16);
            v += __shfl_xor(v, 32);
            acc[k][e] = v;
        }
    int wv = tid >> 6;                      // wave 0..7
    if (((tid >> 3) & 7) == 0) {            // one sub-group per wave writes
#pragma unroll
        for (int k = 0; k < 4; ++k) {
            float4* d0 = (float4*)&red[wv][tl0 + k][0];
            d0[0] = make_float4(acc[k][0], acc[k][1], acc[k][2], acc[k][3]);
            d0[1] = make_float4(acc[k][4], acc[k][5], acc[k][6], acc[k][7]);
        }
    }
    __syncthreads();

    // ---- cross-wave reduce + LN2 (256 lanes = 32 tok x 8 e) ----
    if (tid < TB3 * 8) {
        int rtok = tid >> 3, re = tid & 7;
        float v = 0.f;
#pragma unroll
        for (int w = 0; w < 8; ++w) v += red[w][rtok][re];
        int tok = blockIdx.x * TB3 + rtok;
        v += bb2[re] + x1_lds[rtok][re];

        float s8 = v;
        s8 += __shfl_xor(s8, 1);
        s8 += __shfl_xor(s8, 2);
        s8 += __shfl_xor(s8, 4);
        float mu = s8 * 0.125f;
        float d  = v - mu;
        float vs = d * d;
        vs += __shfl_xor(vs, 1);
        vs += __shfl_xor(vs, 2);
        vs += __shfl_xor(vs, 4);
        float r = rsqrtf(vs * 0.125f + LNEPS);
        out[(size_t)tok * EMB + re] = d * r * g2[re] + b2[re];
    }
}

// ---------------------------------------------------------------------------
extern "C" void kernel_launch(void* const* d_in, const int* in_sizes, int n_in,
                              void* d_out, int out_size, void* d_ws, size_t ws_size,
                              hipStream_t stream) {
    const float* x   = (const float*)d_in[0];
    const float* Wp  = (const float*)d_in[1];
    const float* Wo  = (const float*)d_in[2];
    const float* g1  = (const float*)d_in[3];
    const float* b1  = (const float*)d_in[4];
    const float* W1  = (const float*)d_in[5];
    const float* bb1 = (const float*)d_in[6];
    const float* W2  = (const float*)d_in[7];
    const float* bb2 = (const float*)d_in[8];
    const float* g2  = (const float*)d_in[9];
    const float* b2  = (const float*)d_in[10];
    float* out = (float*)d_out;

    float* ws    = (float*)d_ws;
    float* projH = ws;                // 131072 f32 (head-major)
    float* ctx   = ws + 131072;       // 131072 f32
    float* w2t   = ws + 262144;       // 16384 f32

    hipLaunchKernelGGL(k_prep, dim3(NTOK / 128), dim3(128), 0, stream,
                       x, Wp, W2, projH, w2t);
    hipLaunchKernelGGL(k_attn, dim3((NB * NH) * (SEQ / QCA)), dim3(256), 0, stream,
                       projH, ctx);
    hipLaunchKernelGGL(k_ffn3, dim3(NTOK / TB3), dim3(512), 0, stream,
                       ctx, x, Wo, g1, b1, W1, bb1, w2t, bb2, g2, b2, out);
}

// Round 18
// 53.786 us; speedup vs baseline: 1.0273x; 1.0273x over previous
//
#include <hip/hip_runtime.h>
#include <math.h>

#define NB   8
#define SEQ  2048
#define EMB  8
#define NH   4
#define NFF  2048
#define NTOK (NB*SEQ)          // 16384
#define LNEPS 1e-5f

typedef float v2f __attribute__((ext_vector_type(2)));

__device__ __forceinline__ float fexp2(float x) {
#if __has_builtin(__builtin_amdgcn_exp2f)
    return __builtin_amdgcn_exp2f(x);       // raw v_exp_f32 (~1 ulp)
#else
    return exp2f(x);
#endif
}

__device__ __forceinline__ float dot8(const float4& a, const float4& b,
                                      const float4& c, const float4& d) {
    return a.x*b.x + a.y*b.y + a.z*b.z + a.w*b.w
         + c.x*d.x + c.y*d.y + c.z*d.z + c.w*d.w;
}

// ---------------------------------------------------------------------------
// projH[(b*4+h)][s][2] = (x @ Wp^T) head-major, and W2T[f][e] = W2[e][f]
// ---------------------------------------------------------------------------
__global__ __launch_bounds__(128) void k_prep(const float* __restrict__ x,
                                              const float* __restrict__ Wp,
                                              const float* __restrict__ W2,
                                              float* __restrict__ projH,
                                              float* __restrict__ w2t) {
    int t = blockIdx.x * 128 + threadIdx.x;
    if (t < NTOK) {
        int b = t >> 11, s = t & (SEQ - 1);
        const float4* xr = (const float4*)(x + (size_t)t * EMB);
        float4 xa = xr[0], xb = xr[1];
        float o[8];
#pragma unroll
        for (int e = 0; e < 8; ++e) {
            const float4* wr = (const float4*)(Wp + e * EMB);
            o[e] = dot8(xa, wr[0], xb, wr[1]);
        }
#pragma unroll
        for (int h = 0; h < 4; ++h) {
            *(float2*)(projH + ((size_t)(b * 4 + h) * SEQ + s) * 2) =
                make_float2(o[2 * h], o[2 * h + 1]);
        }
    }
    if (t < NFF) {
        float o[8];
#pragma unroll
        for (int e = 0; e < 8; ++e) o[e] = W2[e * NFF + t];
        float4* wr = (float4*)(w2t + (size_t)t * EMB);
        wr[0] = make_float4(o[0], o[1], o[2], o[3]);
        wr[1] = make_float4(o[4], o[5], o[6], o[7]);
    }
}

// ---------------------------------------------------------------------------
// attention v5 (R16/R17, unchanged): 4 queries/thread, 16 key-subranges x
// 128 keys, QCA=64, grid 1024.  Log2-domain staging (R14-proven): k' = k*C,
// one v_exp_f32 per pair.  ~21 us, near trans-pipe floor (~14 us).
// ---------------------------------------------------------------------------
#define QCA 64
__global__ __launch_bounds__(256) void k_attn(const float* __restrict__ projH,
                                              float* __restrict__ ctx) {
    __shared__ float Kx[SEQ];               // 8 KB  (pre-scaled by C)
    __shared__ float Ky[SEQ];               // 8 KB
    __shared__ float red[3][16][QCA];       // 12 KB

    int bid = blockIdx.x;
    int qc  = bid & 31;                     // 32 query chunks of 64
    int bh  = bid >> 5;                     // (b*4+h)

    const float C   = 1.01001959058f;       // sqrt(log2(e)/sqrt(2))
    const float RC  = 0.99008003302f;       // 1/C
    const float4* gsr = (const float4*)(projH + (size_t)bh * SEQ * 2);
#pragma unroll
    for (int ii = 0; ii < 4; ++ii) {
        int i = threadIdx.x + 256 * ii;
        float4 v = gsr[i];                  // keys 2i,2i+1: (x0,y0,x1,y1)
        *(float2*)&Kx[2 * i] = make_float2(v.x * C, v.z * C);
        *(float2*)&Ky[2 * i] = make_float2(v.y * C, v.w * C);
    }
    __syncthreads();

    int qg  = threadIdx.x & 15;             // 16 query groups of 4
    int sub = threadIdx.x >> 4;             // 16 key subranges of 128

    int q0 = qc * QCA + qg * 4;
    v2f qx2[4], qy2[4], l[4], ax[4], ay[4];
#pragma unroll
    for (int u = 0; u < 4; ++u) {
        float qx = Kx[q0 + u], qy = Ky[q0 + u];   // already x C
        qx2[u] = (v2f){qx, qx};
        qy2[u] = (v2f){qy, qy};
        l[u]  = (v2f){0.f, 0.f};
        ax[u] = (v2f){0.f, 0.f};
        ay[u] = (v2f){0.f, 0.f};
    }

    const float4* Kx4 = (const float4*)Kx;
    const float4* Ky4 = (const float4*)Ky;
    int j04 = sub * 32;                     // 128 keys = 32 float4
#pragma unroll 2
    for (int jj = 0; jj < 32; ++jj) {
        float4 kx = Kx4[j04 + jj];          // 4 distinct addrs/wave: broadcast
        float4 ky = Ky4[j04 + jj];
        v2f k0 = {kx.x, kx.y}, k1 = {kx.z, kx.w};
        v2f m0 = {ky.x, ky.y}, m1 = {ky.z, ky.w};
#pragma unroll
        for (int u = 0; u < 4; ++u) {
            v2f s0 = qx2[u] * k0 + qy2[u] * m0;   // pk mul/fma, log2-domain
            v2f s1 = qx2[u] * k1 + qy2[u] * m1;
            v2f p0, p1;
            p0.x = fexp2(s0.x); p0.y = fexp2(s0.y);
            p1.x = fexp2(s1.x); p1.y = fexp2(s1.y);
            l[u]  += p0;        l[u]  += p1;
            ax[u] += p0 * k0;   ax[u] += p1 * k1;
            ay[u] += p0 * m0;   ay[u] += p1 * m1;
        }
    }
#pragma unroll
    for (int u = 0; u < 4; ++u) {
        red[0][sub][qg * 4 + u] = l[u].x + l[u].y;
        red[1][sub][qg * 4 + u] = ax[u].x + ax[u].y;
        red[2][sub][qg * 4 + u] = ay[u].x + ay[u].y;
    }
    __syncthreads();

    if (threadIdx.x < QCA) {
        float L = 0.f, A0 = 0.f, A1 = 0.f;
#pragma unroll
        for (int s = 0; s < 16; ++s) {
            L  += red[0][s][threadIdx.x];
            A0 += red[1][s][threadIdx.x];
            A1 += red[2][s][threadIdx.x];
        }
        float inv = RC / L;                 // undo the C on staged k
        int b = bh >> 2, h = bh & 3;
        int qglob = qc * QCA + threadIdx.x;
        *(float2*)(ctx + ((size_t)b * SEQ + qglob) * EMB + 2 * h) =
            make_float2(A0 * inv, A1 * inv);
    }
}

// ---------------------------------------------------------------------------
// FUSED post+FFN v9: TOKEN-PAIR PACKED inner loop.  Same memory pattern,
// layouts, and reduce structure as R14-proven ffn3 (TB=32, 512 thr,
// grid 512, sub=tid>>3 strided-f, tg=tid&7 4 tok/thread) — ONLY the inner
// math is repacked: d2 = {dot_t0, dot_t1} via pk chains (no horizontal
// ops, unlike R8's failed e-dim packing), acc2[p][e] = {acc_t0, acc_t1}.
// 68 -> ~38 VALU instrs per (4tok x f) iter.
// ---------------------------------------------------------------------------
#define TB3  32                 // tokens per block
#define FCH3 32                 // f rows per thread
__global__ __launch_bounds__(512) void k_ffn6(const float* __restrict__ ctx,
                                              const float* __restrict__ x,
                                              const float* __restrict__ Wo,
                                              const float* __restrict__ g1,
                                              const float* __restrict__ b1,
                                              const float* __restrict__ W1,
                                              const float* __restrict__ bb1,
                                              const float* __restrict__ w2t,
                                              const float* __restrict__ bb2,
                                              const float* __restrict__ g2,
                                              const float* __restrict__ b2,
                                              float* __restrict__ out) {
    __shared__ float q_lds[TB3][8];         // 1 KB
    __shared__ float x1_lds[TB3][8];        // 1 KB
    __shared__ float red[8][TB3][8];        // 8 KB: per-wave partials

    int tid = threadIdx.x;

    // ---- prologue: post-attention for this block's 32 tokens (256 lanes) ----
    if (tid < TB3 * 8) {
        int tl = tid >> 3, e = tid & 7;
        int tok = blockIdx.x * TB3 + tl;
        const float4* cr = (const float4*)(ctx + (size_t)tok * EMB);
        float4 ca = cr[0], cb = cr[1];      // broadcast across the 8 lanes
        const float4* wr = (const float4*)(Wo + e * EMB);
        float ao = dot8(ca, wr[0], cb, wr[1]);
        float y = x[(size_t)tok * EMB + e] + ao;

        float s8 = y;
        s8 += __shfl_xor(s8, 1);
        s8 += __shfl_xor(s8, 2);
        s8 += __shfl_xor(s8, 4);
        float mu = s8 * 0.125f;
        float d  = y - mu;
        float vs = d * d;
        vs += __shfl_xor(vs, 1);
        vs += __shfl_xor(vs, 2);
        vs += __shfl_xor(vs, 4);
        float r = rsqrtf(vs * 0.125f + LNEPS);
        float v = d * r * g1[e] + b1[e];
        x1_lds[tl][e] = v;

        float p = __cosf(v);
        float t1 = __shfl_up(p, 1, 8); p = (e >= 1) ? p * t1 : p;
        float t2 = __shfl_up(p, 2, 8); p = (e >= 2) ? p * t2 : p;
        float t4 = __shfl_up(p, 4, 8); p = (e >= 4) ? p * t4 : p;
        q_lds[tl][e] = p;
    }
    __syncthreads();

    // ---- main FFN loop: 2 token-pairs x 32 sequential f rows per thread ----
    int tg  = tid & 7;                      // 8 token groups x 4 tokens
    int sub = tid >> 3;                     // 64 f-subranges
    int tl0 = tg * 4;

    v2f q2[2][8];                           // {q_t0[e], q_t1[e]} per pair
#pragma unroll
    for (int p = 0; p < 2; ++p)
#pragma unroll
        for (int e = 0; e < 8; ++e)
            q2[p][e] = (v2f){q_lds[tl0 + 2 * p][e], q_lds[tl0 + 2 * p + 1][e]};

    v2f acc2[2][8];
#pragma unroll
    for (int p = 0; p < 2; ++p)
#pragma unroll
        for (int e = 0; e < 8; ++e) acc2[p][e] = (v2f){0.f, 0.f};

    int f0 = sub * FCH3;
#pragma unroll 4
    for (int i = 0; i < FCH3; ++i) {
        int f = f0 + i;                     // walks consecutive rows: L1 reuse
        const float4* w1r = (const float4*)(W1 + (size_t)f * EMB);
        float4 wa = w1r[0], wb = w1r[1];
        float bias = bb1[f];
        const float4* w2r = (const float4*)(w2t + (size_t)f * EMB);
        float4 va = w2r[0], vb = w2r[1];
        float wsr[8] = {wa.x, wa.y, wa.z, wa.w, wb.x, wb.y, wb.z, wb.w};
        float vsr[8] = {va.x, va.y, va.z, va.w, vb.x, vb.y, vb.z, vb.w};
#pragma unroll
        for (int p = 0; p < 2; ++p) {
            v2f d2 = q2[p][0] * (v2f){wsr[0], wsr[0]};
#pragma unroll
            for (int e = 1; e < 8; ++e)
                d2 += q2[p][e] * (v2f){wsr[e], wsr[e]};   // pk_fma chain
            v2f h2;
            h2.x = fmaxf(d2.x + bias, 0.f);
            h2.y = fmaxf(d2.y + bias, 0.f);
#pragma unroll
            for (int e = 0; e < 8; ++e)
                acc2[p][e] += h2 * (v2f){vsr[e], vsr[e]}; // pk_fma accum
        }
    }

    // unpack token pairs, then reduce exactly as R14
    float acc[4][8];
#pragma unroll
    for (int p = 0; p < 2; ++p)
#pragma unroll
        for (int e = 0; e < 8; ++e) {
            acc[2 * p][e]     = acc2[p][e].x;
            acc[2 * p + 1][e] = acc2[p][e].y;
        }

    // in-wave reduce across the 8 sub groups (lane bits 3..5)
#pragma unroll
    for (int k = 0; k < 4; ++k)
#pragma unroll
        for (int e = 0; e < 8; ++e) {
            float v = acc[k][e];
            v += __shfl_xor(v, 8);
            v += __shfl_xor(v, 16);
            v += __shfl_xor(v, 32);
            acc[k][e] = v;
        }
    int wv = tid >> 6;                      // wave 0..7
    if (((tid >> 3) & 7) == 0) {            // one sub-group per wave writes
#pragma unroll
        for (int k = 0; k < 4; ++k) {
            float4* d0 = (float4*)&red[wv][tl0 + k][0];
            d0[0] = make_float4(acc[k][0], acc[k][1], acc[k][2], acc[k][3]);
            d0[1] = make_float4(acc[k][4], acc[k][5], acc[k][6], acc[k][7]);
        }
    }
    __syncthreads();

    // ---- cross-wave reduce + LN2 (256 lanes = 32 tok x 8 e) ----
    if (tid < TB3 * 8) {
        int rtok = tid >> 3, re = tid & 7;
        float v = 0.f;
#pragma unroll
        for (int w = 0; w < 8; ++w) v += red[w][rtok][re];
        int tok = blockIdx.x * TB3 + rtok;
        v += bb2[re] + x1_lds[rtok][re];

        float s8 = v;
        s8 += __shfl_xor(s8, 1);
        s8 += __shfl_xor(s8, 2);
        s8 += __shfl_xor(s8, 4);
        float mu = s8 * 0.125f;
        float d  = v - mu;
        float vs = d * d;
        vs += __shfl_xor(vs, 1);
        vs += __shfl_xor(vs, 2);
        vs += __shfl_xor(vs, 4);
        float r = rsqrtf(vs * 0.125f + LNEPS);
        out[(size_t)tok * EMB + re] = d * r * g2[re] + b2[re];
    }
}

// ---------------------------------------------------------------------------
extern "C" void kernel_launch(void* const* d_in, const int* in_sizes, int n_in,
                              void* d_out, int out_size, void* d_ws, size_t ws_size,
                              hipStream_t stream) {
    const float* x   = (const float*)d_in[0];
    const float* Wp  = (const float*)d_in[1];
    const float* Wo  = (const float*)d_in[2];
    const float* g1  = (const float*)d_in[3];
    const float* b1  = (const float*)d_in[4];
    const float* W1  = (const float*)d_in[5];
    const float* bb1 = (const float*)d_in[6];
    const float* W2  = (const float*)d_in[7];
    const float* bb2 = (const float*)d_in[8];
    const float* g2  = (const float*)d_in[9];
    const float* b2  = (const float*)d_in[10];
    float* out = (float*)d_out;

    float* ws    = (float*)d_ws;
    float* projH = ws;                // 131072 f32 (head-major)
    float* ctx   = ws + 131072;       // 131072 f32
    float* w2t   = ws + 262144;       // 16384 f32

    hipLaunchKernelGGL(k_prep, dim3(NTOK / 128), dim3(128), 0, stream,
                       x, Wp, W2, projH, w2t);
    hipLaunchKernelGGL(k_attn, dim3((NB * NH) * (SEQ / QCA)), dim3(256), 0, stream,
                       projH, ctx);
    hipLaunchKernelGGL(k_ffn6, dim3(NTOK / TB3), dim3(512), 0, stream,
                       ctx, x, Wo, g1, b1, W1, bb1, w2t, bb2, g2, b2, out);
}

// Round 19
// 48.863 us; speedup vs baseline: 1.1308x; 1.1008x over previous
//
#include <hip/hip_runtime.h>
#include <math.h>

#define NB   8
#define SEQ  2048
#define EMB  8
#define NH   4
#define NFF  2048
#define NTOK (NB*SEQ)          // 16384
#define LNEPS 1e-5f

typedef float v2f __attribute__((ext_vector_type(2)));

__device__ __forceinline__ float fexp2(float x) {
#if __has_builtin(__builtin_amdgcn_exp2f)
    return __builtin_amdgcn_exp2f(x);       // raw v_exp_f32 (~1 ulp)
#else
    return exp2f(x);
#endif
}

__device__ __forceinline__ float dot8(const float4& a, const float4& b,
                                      const float4& c, const float4& d) {
    return a.x*b.x + a.y*b.y + a.z*b.z + a.w*b.w
         + c.x*d.x + c.y*d.y + c.z*d.z + c.w*d.w;
}

// ---------------------------------------------------------------------------
// projH[(b*4+h)][s][2] = (x @ Wp^T) head-major, and W2T[f][e] = W2[e][f]
// ---------------------------------------------------------------------------
__global__ __launch_bounds__(128) void k_prep(const float* __restrict__ x,
                                              const float* __restrict__ Wp,
                                              const float* __restrict__ W2,
                                              float* __restrict__ projH,
                                              float* __restrict__ w2t) {
    int t = blockIdx.x * 128 + threadIdx.x;
    if (t < NTOK) {
        int b = t >> 11, s = t & (SEQ - 1);
        const float4* xr = (const float4*)(x + (size_t)t * EMB);
        float4 xa = xr[0], xb = xr[1];
        float o[8];
#pragma unroll
        for (int e = 0; e < 8; ++e) {
            const float4* wr = (const float4*)(Wp + e * EMB);
            o[e] = dot8(xa, wr[0], xb, wr[1]);
        }
#pragma unroll
        for (int h = 0; h < 4; ++h) {
            *(float2*)(projH + ((size_t)(b * 4 + h) * SEQ + s) * 2) =
                make_float2(o[2 * h], o[2 * h + 1]);
        }
    }
    if (t < NFF) {
        float o[8];
#pragma unroll
        for (int e = 0; e < 8; ++e) o[e] = W2[e * NFF + t];
        float4* wr = (float4*)(w2t + (size_t)t * EMB);
        wr[0] = make_float4(o[0], o[1], o[2], o[3]);
        wr[1] = make_float4(o[4], o[5], o[6], o[7]);
    }
}

// ---------------------------------------------------------------------------
// attention v5 (R16/R17, unchanged): 4 queries/thread, 16 key-subranges x
// 128 keys, QCA=64, grid 1024.  Log2-domain staging (R14-proven): k' = k*C,
// one v_exp_f32 per pair.
// ---------------------------------------------------------------------------
#define QCA 64
__global__ __launch_bounds__(256) void k_attn(const float* __restrict__ projH,
                                              float* __restrict__ ctx) {
    __shared__ float Kx[SEQ];               // 8 KB  (pre-scaled by C)
    __shared__ float Ky[SEQ];               // 8 KB
    __shared__ float red[3][16][QCA];       // 12 KB

    int bid = blockIdx.x;
    int qc  = bid & 31;                     // 32 query chunks of 64
    int bh  = bid >> 5;                     // (b*4+h)

    const float C   = 1.01001959058f;       // sqrt(log2(e)/sqrt(2))
    const float RC  = 0.99008003302f;       // 1/C
    const float4* gsr = (const float4*)(projH + (size_t)bh * SEQ * 2);
#pragma unroll
    for (int ii = 0; ii < 4; ++ii) {
        int i = threadIdx.x + 256 * ii;
        float4 v = gsr[i];                  // keys 2i,2i+1: (x0,y0,x1,y1)
        *(float2*)&Kx[2 * i] = make_float2(v.x * C, v.z * C);
        *(float2*)&Ky[2 * i] = make_float2(v.y * C, v.w * C);
    }
    __syncthreads();

    int qg  = threadIdx.x & 15;             // 16 query groups of 4
    int sub = threadIdx.x >> 4;             // 16 key subranges of 128

    int q0 = qc * QCA + qg * 4;
    v2f qx2[4], qy2[4], l[4], ax[4], ay[4];
#pragma unroll
    for (int u = 0; u < 4; ++u) {
        float qx = Kx[q0 + u], qy = Ky[q0 + u];   // already x C
        qx2[u] = (v2f){qx, qx};
        qy2[u] = (v2f){qy, qy};
        l[u]  = (v2f){0.f, 0.f};
        ax[u] = (v2f){0.f, 0.f};
        ay[u] = (v2f){0.f, 0.f};
    }

    const float4* Kx4 = (const float4*)Kx;
    const float4* Ky4 = (const float4*)Ky;
    int j04 = sub * 32;                     // 128 keys = 32 float4
#pragma unroll 2
    for (int jj = 0; jj < 32; ++jj) {
        float4 kx = Kx4[j04 + jj];          // 4 distinct addrs/wave: broadcast
        float4 ky = Ky4[j04 + jj];
        v2f k0 = {kx.x, kx.y}, k1 = {kx.z, kx.w};
        v2f m0 = {ky.x, ky.y}, m1 = {ky.z, ky.w};
#pragma unroll
        for (int u = 0; u < 4; ++u) {
            v2f s0 = qx2[u] * k0 + qy2[u] * m0;   // pk mul/fma, log2-domain
            v2f s1 = qx2[u] * k1 + qy2[u] * m1;
            v2f p0, p1;
            p0.x = fexp2(s0.x); p0.y = fexp2(s0.y);
            p1.x = fexp2(s1.x); p1.y = fexp2(s1.y);
            l[u]  += p0;        l[u]  += p1;
            ax[u] += p0 * k0;   ax[u] += p1 * k1;
            ay[u] += p0 * m0;   ay[u] += p1 * m1;
        }
    }
#pragma unroll
    for (int u = 0; u < 4; ++u) {
        red[0][sub][qg * 4 + u] = l[u].x + l[u].y;
        red[1][sub][qg * 4 + u] = ax[u].x + ax[u].y;
        red[2][sub][qg * 4 + u] = ay[u].x + ay[u].y;
    }
    __syncthreads();

    if (threadIdx.x < QCA) {
        float L = 0.f, A0 = 0.f, A1 = 0.f;
#pragma unroll
        for (int s = 0; s < 16; ++s) {
            L  += red[0][s][threadIdx.x];
            A0 += red[1][s][threadIdx.x];
            A1 += red[2][s][threadIdx.x];
        }
        float inv = RC / L;                 // undo the C on staged k
        int b = bh >> 2, h = bh & 3;
        int qglob = qc * QCA + threadIdx.x;
        *(float2*)(ctx + ((size_t)b * SEQ + qglob) * EMB + 2 * h) =
            make_float2(A0 * inv, A1 * inv);
    }
}

// ---------------------------------------------------------------------------
// FUSED post+FFN v10: HYBRID — 8 tokens/thread (VMEM/pair halved, R16)
// x token-pair packing (VALU/pair halved, R18).  512 threads, TB=64,
// grid=256 (1 block/CU, ~2 waves/SIMD at VGPR~160 — betting on
// issue-count, not occupancy, being the binder).  tg=tid&7: 8 tokens as
// 4 pairs; sub=tid>>3: 64 f-subranges, strided-f (L1 line reuse).
// Reduce structure identical to ffn3/ffn6.
// ---------------------------------------------------------------------------
#define TB3  64                 // tokens per block
#define FCH3 32                 // f rows per thread
__global__ __launch_bounds__(512) void k_ffn7(const float* __restrict__ ctx,
                                              const float* __restrict__ x,
                                              const float* __restrict__ Wo,
                                              const float* __restrict__ g1,
                                              const float* __restrict__ b1,
                                              const float* __restrict__ W1,
                                              const float* __restrict__ bb1,
                                              const float* __restrict__ w2t,
                                              const float* __restrict__ bb2,
                                              const float* __restrict__ g2,
                                              const float* __restrict__ b2,
                                              float* __restrict__ out) {
    __shared__ float q_lds[TB3][8];         // 2 KB
    __shared__ float x1_lds[TB3][8];        // 2 KB
    __shared__ float red[8][TB3][8];        // 16 KB: per-wave partials

    int tid = threadIdx.x;

    // ---- prologue: post-attention for this block's 64 tokens (512 lanes) ----
    {
        int tl = tid >> 3, e = tid & 7;
        int tok = blockIdx.x * TB3 + tl;
        const float4* cr = (const float4*)(ctx + (size_t)tok * EMB);
        float4 ca = cr[0], cb = cr[1];      // broadcast across the 8 lanes
        const float4* wr = (const float4*)(Wo + e * EMB);
        float ao = dot8(ca, wr[0], cb, wr[1]);
        float y = x[(size_t)tok * EMB + e] + ao;

        float s8 = y;
        s8 += __shfl_xor(s8, 1);
        s8 += __shfl_xor(s8, 2);
        s8 += __shfl_xor(s8, 4);
        float mu = s8 * 0.125f;
        float d  = y - mu;
        float vs = d * d;
        vs += __shfl_xor(vs, 1);
        vs += __shfl_xor(vs, 2);
        vs += __shfl_xor(vs, 4);
        float r = rsqrtf(vs * 0.125f + LNEPS);
        float v = d * r * g1[e] + b1[e];
        x1_lds[tl][e] = v;

        float p = __cosf(v);
        float t1 = __shfl_up(p, 1, 8); p = (e >= 1) ? p * t1 : p;
        float t2 = __shfl_up(p, 2, 8); p = (e >= 2) ? p * t2 : p;
        float t4 = __shfl_up(p, 4, 8); p = (e >= 4) ? p * t4 : p;
        q_lds[tl][e] = p;
    }
    __syncthreads();

    // ---- main FFN loop: 4 token-pairs x 32 sequential f rows per thread ----
    int tg  = tid & 7;                      // 8 token groups x 8 tokens
    int sub = tid >> 3;                     // 64 f-subranges
    int tl0 = tg * 8;

    v2f q2[4][8];                           // {q_t0[e], q_t1[e]} per pair
#pragma unroll
    for (int p = 0; p < 4; ++p)
#pragma unroll
        for (int e = 0; e < 8; ++e)
            q2[p][e] = (v2f){q_lds[tl0 + 2 * p][e], q_lds[tl0 + 2 * p + 1][e]};

    v2f acc2[4][8];
#pragma unroll
    for (int p = 0; p < 4; ++p)
#pragma unroll
        for (int e = 0; e < 8; ++e) acc2[p][e] = (v2f){0.f, 0.f};

    int f0 = sub * FCH3;
#pragma unroll 2
    for (int i = 0; i < FCH3; ++i) {
        int f = f0 + i;                     // walks consecutive rows: L1 reuse
        const float4* w1r = (const float4*)(W1 + (size_t)f * EMB);
        float4 wa = w1r[0], wb = w1r[1];
        float bias = bb1[f];
        const float4* w2r = (const float4*)(w2t + (size_t)f * EMB);
        float4 va = w2r[0], vb = w2r[1];
        float wsr[8] = {wa.x, wa.y, wa.z, wa.w, wb.x, wb.y, wb.z, wb.w};
        float vsr[8] = {va.x, va.y, va.z, va.w, vb.x, vb.y, vb.z, vb.w};
#pragma unroll
        for (int p = 0; p < 4; ++p) {
            v2f d2 = q2[p][0] * (v2f){wsr[0], wsr[0]};
#pragma unroll
            for (int e = 1; e < 8; ++e)
                d2 += q2[p][e] * (v2f){wsr[e], wsr[e]};   // pk_fma chain
            v2f h2;
            h2.x = fmaxf(d2.x + bias, 0.f);
            h2.y = fmaxf(d2.y + bias, 0.f);
#pragma unroll
            for (int e = 0; e < 8; ++e)
                acc2[p][e] += h2 * (v2f){vsr[e], vsr[e]}; // pk_fma accum
        }
    }

    // unpack token pairs, then reduce exactly as before
    float acc[8][8];
#pragma unroll
    for (int p = 0; p < 4; ++p)
#pragma unroll
        for (int e = 0; e < 8; ++e) {
            acc[2 * p][e]     = acc2[p][e].x;
            acc[2 * p + 1][e] = acc2[p][e].y;
        }

    // in-wave reduce across the 8 sub groups (lane bits 3..5)
#pragma unroll
    for (int k = 0; k < 8; ++k)
#pragma unroll
        for (int e = 0; e < 8; ++e) {
            float v = acc[k][e];
            v += __shfl_xor(v, 8);
            v += __shfl_xor(v, 16);
            v += __shfl_xor(v, 32);
            acc[k][e] = v;
        }
    int wv = tid >> 6;                      // wave 0..7
    if (((tid >> 3) & 7) == 0) {            // one sub-group per wave writes
#pragma unroll
        for (int k = 0; k < 8; ++k) {
            float4* d0 = (float4*)&red[wv][tl0 + k][0];
            d0[0] = make_float4(acc[k][0], acc[k][1], acc[k][2], acc[k][3]);
            d0[1] = make_float4(acc[k][4], acc[k][5], acc[k][6], acc[k][7]);
        }
    }
    __syncthreads();

    // ---- cross-wave reduce + LN2 (512 lanes = 64 tok x 8 e) ----
    {
        int rtok = tid >> 3, re = tid & 7;
        float v = 0.f;
#pragma unroll
        for (int w = 0; w < 8; ++w) v += red[w][rtok][re];
        int tok = blockIdx.x * TB3 + rtok;
        v += bb2[re] + x1_lds[rtok][re];

        float s8 = v;
        s8 += __shfl_xor(s8, 1);
        s8 += __shfl_xor(s8, 2);
        s8 += __shfl_xor(s8, 4);
        float mu = s8 * 0.125f;
        float d  = v - mu;
        float vs = d * d;
        vs += __shfl_xor(vs, 1);
        vs += __shfl_xor(vs, 2);
        vs += __shfl_xor(vs, 4);
        float r = rsqrtf(vs * 0.125f + LNEPS);
        out[(size_t)tok * EMB + re] = d * r * g2[re] + b2[re];
    }
}

// ---------------------------------------------------------------------------
extern "C" void kernel_launch(void* const* d_in, const int* in_sizes, int n_in,
                              void* d_out, int out_size, void* d_ws, size_t ws_size,
                              hipStream_t stream) {
    const float* x   = (const float*)d_in[0];
    const float* Wp  = (const float*)d_in[1];
    const float* Wo  = (const float*)d_in[2];
    const float* g1  = (const float*)d_in[3];
    const float* b1  = (const float*)d_in[4];
    const float* W1  = (const float*)d_in[5];
    const float* bb1 = (const float*)d_in[6];
    const float* W2  = (const float*)d_in[7];
    const float* bb2 = (const float*)d_in[8];
    const float* g2  = (const float*)d_in[9];
    const float* b2  = (const float*)d_in[10];
    float* out = (float*)d_out;

    float* ws    = (float*)d_ws;
    float* projH = ws;                // 131072 f32 (head-major)
    float* ctx   = ws + 131072;       // 131072 f32
    float* w2t   = ws + 262144;       // 16384 f32

    hipLaunchKernelGGL(k_prep, dim3(NTOK / 128), dim3(128), 0, stream,
                       x, Wp, W2, projH, w2t);
    hipLaunchKernelGGL(k_attn, dim3((NB * NH) * (SEQ / QCA)), dim3(256), 0, stream,
                       projH, ctx);
    hipLaunchKernelGGL(k_ffn7, dim3(NTOK / TB3), dim3(512), 0, stream,
                       ctx, x, Wo, g1, b1, W1, bb1, w2t, bb2, g2, b2, out);
}